// Round 11
// baseline (139.570 us; speedup 1.0000x reference)
//
#include <hip/hip_runtime.h>

// ContextualAttention: out[b,c,p] = sum_k K[b,k,c] * softmax_k( K[b,:,:] @ F[b,:,p] )
// K = rowwise-normalized (F^T + eps). Flash-style fusion, bf16 MFMA, f32 accum.
// Round 10: r9 skeleton (q=128/block, 1 block/CU, producer/consumer, KT=64) +
//   consumer GEMM2 on 32x32x16 MFMA (4 indep 4-deep chains; KB image relaid
//   as [jt][kc][c][32B] for coalesced 32x32 A-frag loads) + asymmetric
//   setprio (producer prio over its whole phase; consumer none).

#define BATCH 8
#define CH 256
#define NPIX 4096
#define EPSV 1e-7f
#define L2E 1.4426950408889634f

using bf16x8 = __attribute__((ext_vector_type(8))) __bf16;
using bf16x4 = __attribute__((ext_vector_type(4))) __bf16;
using f32x4  = __attribute__((ext_vector_type(4))) float;
using f32x16 = __attribute__((ext_vector_type(16))) float;

__device__ __forceinline__ void gload16(const void* g, void* l) {
  __builtin_amdgcn_global_load_lds(
      (const __attribute__((address_space(1))) unsigned int*)g,
      (__attribute__((address_space(3))) unsigned int*)l, 16, 0, 0);
}

// producer barrier: full drain (its global_load_lds results are read by OTHER
// producer waves next phase; P writes must be visible).
__device__ __forceinline__ void barrier_full() {
  asm volatile("s_waitcnt vmcnt(0) lgkmcnt(0)\n"
               "s_barrier" ::: "memory");
}
// consumer barrier: LDS-only drain; its global->reg prefetch stays in flight.
__device__ __forceinline__ void barrier_lgkm() {
  asm volatile("s_waitcnt lgkmcnt(0)\n"
               "s_barrier" ::: "memory");
}

// ============================================================================
// Prep: per (batch, 32-key tile): inv-norms, normalized bf16 K, two images:
//   KA[b][kt][32 k][256 c]: 16B-unit u stored at u ^ (k&7)   (GEMM1 LDS image)
//   KB[b][jt][kc 0..3][256 c][32B]: 32x32-A-frag layout      (GEMM2 L2 image)
//     jt = kt>>1 (64-k phase tile), kc = k/16, byte = (k&15 -> hi*16 + j*2)
// ============================================================================
__global__ __launch_bounds__(256)
void ca_prep(const float* __restrict__ F, __bf16* __restrict__ KA,
             __bf16* __restrict__ KB) {
  const int b   = blockIdx.x;
  const int kt  = blockIdx.y;          // 128 tiles of 32 keys
  const int kt0 = kt * 32;
  const int t   = threadIdx.x;
  const int k   = t & 31;
  const int h   = (t >> 5) & 1;
  const int w   = t >> 6;

  const float* __restrict__ Fb = F + (size_t)b * CH * NPIX;

  __shared__ float red[4][32];
  __shared__ float invk[32];
  __shared__ __align__(16) __bf16 T[32][264];   // +8 pad

  float fv[32];
  float ss = 0.f;
#pragma unroll
  for (int rep = 0; rep < 32; ++rep) {
    int c = rep * 8 + w * 2 + h;
    float v = Fb[(size_t)c * NPIX + kt0 + k] + EPSV;
    fv[rep] = v;
    ss = fmaf(v, v, ss);
  }
  ss += __shfl_xor(ss, 32, 64);
  if ((t & 32) == 0) red[w][k] = ss;
  __syncthreads();
  if (t < 32) invk[t] = rsqrtf(red[0][t] + red[1][t] + red[2][t] + red[3][t]);
  __syncthreads();
  const float iv = invk[k];
#pragma unroll
  for (int rep = 0; rep < 32; ++rep) {
    int c = rep * 8 + w * 2 + h;
    T[k][c] = (__bf16)(fv[rep] * iv);
  }
  __syncthreads();

  // KA image (swizzled for LDS ds_read)
  __bf16* KAp = KA + ((size_t)b * 128 + kt) * (32 * 256);
#pragma unroll
  for (int pass = 0; pass < 4; ++pass) {
    int kk = pass * 8 + (t >> 5);
    int u  = t & 31;
    bf16x8 v = *(const bf16x8*)&T[kk][u * 8];
    *(bf16x8*)&KAp[kk * 256 + ((u ^ (kk & 7)) * 8)] = v;
  }
  // KB image: chunk (jt, kc): [256 c][32B], lane writes 8 k-contig = 16B
  {
    const int jt = kt >> 1;
    char* KBp = (char*)KB + ((size_t)b * 64 + jt) * 32768;
#pragma unroll
    for (int pass = 0; pass < 4; ++pass) {
      int c  = pass * 64 + (t >> 2);
      int v  = t & 3;                       // klocal = v*8 + j
      int kc = (kt & 1) * 2 + (v >> 1);     // global k chunk of 16
      int hi = v & 1;
      bf16x8 o;
#pragma unroll
      for (int j = 0; j < 8; ++j) o[j] = T[v * 8 + j][c];
      *(bf16x8*)(KBp + kc * 8192 + c * 32 + hi * 16) = o;
    }
  }
}

// ============================================================================
// Fused attention, producer/consumer, q=128/block, KT=64 fat phases.
// Grid (8 batch, 32 q-tiles), 1024 threads = 16 waves, 1 block/CU.
//   waves 0-7  (producer): (kh = w>>2, qh = w&3) -> 32k x 32q GEMM1 + softmax
//   waves 8-15 (consumer): cq = w-8: c0 = (cq>>1)*64, q-half = (cq&1)*64,
//                          GEMM2 on 32x32x16 (2x2 tiles of 32c x 32q)
// smem (96KB): [0,64K) KA dbuf; [64K,96K) P dbuf (P[128 q][64 k], 128B rows,
//   16B-unit u = k/8 stored at u^(q&7)); lE[2][128] aliased at smem+0.
// 66 barriers per role.
// ============================================================================
__global__ __launch_bounds__(1024, 4)
void ca_attn10(const float* __restrict__ F, const __bf16* __restrict__ KA,
               const __bf16* __restrict__ KB, float* __restrict__ Out) {
  __shared__ __align__(16) char smem[98304];

  const int tid  = threadIdx.x;
  const int lane = tid & 63;
  const int w    = tid >> 6;            // 0..15
  const int lq   = lane & 15;
  const int lg   = lane >> 4;
  const int b    = blockIdx.x;          // batch fastest -> one batch per XCD
  const int q0   = blockIdx.y * 128;

  const char* KAb = (const char*)(KA + (size_t)b * (size_t)NPIX * CH);
  const char* KBb = (const char*)(KB + (size_t)b * (size_t)NPIX * CH);
  char* PlB = smem + 65536;

  if (w < 8) {
    // =================== producer: GEMM1 + softmax ========================
    const int kh = w >> 2, qh = w & 3;
    const int qA = q0 + qh * 32 + lq;
    const int qB = qA + 16;
    const float* __restrict__ Fb = F + (size_t)b * CH * NPIX;
    const int wo = w * 4096;            // this wave's 4KB slice of a 32KB tile

    // stage tile 0 -> buf 0 (overlaps Q loads below)
#pragma unroll
    for (int j = 0; j < 4; ++j)
      gload16(KAb + wo + j * 1024 + lane * 16, smem + wo + j * 1024);

    // Q fragments (pre-scaled by L2E) + squared norms for the fixed shift
    bf16x8 qfA[8], qfB[8];
    float ssA = 0.f, ssB = 0.f;
#pragma unroll
    for (int cf = 0; cf < 8; ++cf) {
#pragma unroll
      for (int j = 0; j < 8; ++j) {
        int c = cf * 32 + lg * 8 + j;
        float va = Fb[(size_t)c * NPIX + qA];
        float vb = Fb[(size_t)c * NPIX + qB];
        qfA[cf][j] = (__bf16)(va * L2E);
        qfB[cf][j] = (__bf16)(vb * L2E);
        ssA = fmaf(va, va, ssA);
        ssB = fmaf(vb, vb, ssB);
      }
    }
    ssA += __shfl_xor(ssA, 16, 64); ssA += __shfl_xor(ssA, 32, 64);
    ssB += __shfl_xor(ssB, 16, 64); ssB += __shfl_xor(ssB, 32, 64);
    // m_q = ||F_q||: provable max of S[:,q] (K rows unit-norm), exact shift.
    const float mqA = sqrtf(ssA) * L2E, mqB = sqrtf(ssB) * L2E;

    float lA = 0.f, lB = 0.f;
    const int krow = kh * 16 + lq;      // A row within each 32k sub-tile
    const int ksw  = lq & 7;
    const int rowByte = krow * 512;
    // P write: row q (128B), unit u = ts*4 + kh*2 + (lg>>1), u ^= (q&7)=lq&7,
    // + (lg&1)*8 bytes within unit.  (k = u*8 + (lg&1)*4 + r)
    const int pwRowA = (qh * 32 + lq) * 128;
    const int pwRowB = pwRowA + 16 * 128;
    const int puBase = kh * 2 + (lg >> 1);
    const int pwSub  = ((lg & 1) << 3);
    const int u0 = (puBase ^ ksw) << 4;          // sub-tile 0 unit offset
    const int u1 = ((4 + puBase) ^ ksw) << 4;    // sub-tile 1 unit offset

    barrier_full();                                  // #1: tile 0 landed

    const f32x4 zero = {0.f, 0.f, 0.f, 0.f};
    for (int i = 0; i < 64; ++i) {
      const int cb = i & 1;
      if (i < 63) {                                  // stage tile i+1
        const char* s = KAb + (size_t)(i + 1) * 32768;
        char* d = smem + (cb ^ 1) * 32768;
#pragma unroll
        for (int j = 0; j < 4; ++j)
          gload16(s + wo + j * 1024 + lane * 16, d + wo + j * 1024);
      }

      __builtin_amdgcn_s_setprio(1);   // producer path defines the phase

      // GEMM1: 4 independent 8-deep chains (2 sub-tiles x 2 q-frags)
      const char* ab0 = smem + cb * 32768 + rowByte;          // sub-tile 0
      const char* ab1 = ab0 + 16384;                          // sub-tile 1
      f32x4 s00 = zero, s01 = zero, s10 = zero, s11 = zero;
#pragma unroll
      for (int cf = 0; cf < 8; ++cf) {
        const int uo = ((((cf << 2) | lg) ^ ksw) << 4);
        bf16x8 a0 = *(const bf16x8*)(ab0 + uo);
        bf16x8 a1 = *(const bf16x8*)(ab1 + uo);
        s00 = __builtin_amdgcn_mfma_f32_16x16x32_bf16(a0, qfA[cf], s00, 0, 0, 0);
        s01 = __builtin_amdgcn_mfma_f32_16x16x32_bf16(a0, qfB[cf], s01, 0, 0, 0);
        s10 = __builtin_amdgcn_mfma_f32_16x16x32_bf16(a1, qfA[cf], s10, 0, 0, 0);
        s11 = __builtin_amdgcn_mfma_f32_16x16x32_bf16(a1, qfB[cf], s11, 0, 0, 0);
      }

      // softmax numerators (fixed shift), write P
      char* pb = PlB + cb * 16384;
      bf16x4 pv00, pv01, pv10, pv11;
#pragma unroll
      for (int r = 0; r < 4; ++r) {
        float p00 = __builtin_amdgcn_exp2f(s00[r] - mqA);
        float p01 = __builtin_amdgcn_exp2f(s01[r] - mqB);
        float p10 = __builtin_amdgcn_exp2f(s10[r] - mqA);
        float p11 = __builtin_amdgcn_exp2f(s11[r] - mqB);
        lA += p00 + p10; lB += p01 + p11;
        pv00[r] = (__bf16)p00; pv01[r] = (__bf16)p01;
        pv10[r] = (__bf16)p10; pv11[r] = (__bf16)p11;
      }
      *(bf16x4*)(pb + pwRowA + u0 + pwSub) = pv00;
      *(bf16x4*)(pb + pwRowB + u0 + pwSub) = pv01;
      *(bf16x4*)(pb + pwRowA + u1 + pwSub) = pv10;
      *(bf16x4*)(pb + pwRowB + u1 + pwSub) = pv11;
      __builtin_amdgcn_s_setprio(0);

      barrier_full();                                // #i+2
    }

    // final softmax denominators -> lE (aliased at smem+0; KA buf0 is dead)
    lA += __shfl_xor(lA, 16, 64); lA += __shfl_xor(lA, 32, 64);
    lB += __shfl_xor(lB, 16, 64); lB += __shfl_xor(lB, 32, 64);
    float* lE = (float*)smem;
    if (lg == 0) lE[kh * 128 + qh * 32 + lq] = lA;
    if (lg == 1) lE[kh * 128 + qh * 32 + 16 + lq] = lB;
    barrier_full();                                  // #66

  } else {
    // =================== consumer: GEMM2 (32x32x16) =======================
    const int cq  = w - 8;
    const int c0  = (cq >> 1) * 64;
    const int qh2 = cq & 1;                          // q-half (64 q)
    const int l31 = lane & 31;
    const int hi  = lane >> 5;
    // KB frag: chunk kc at jt*32768 + kc*8192 + (c0+ct*32+l31)*32 + hi*16
    const size_t cBase = (size_t)(c0 + l31) * 32 + (size_t)hi * 16;
    // P frag: row q = qh2*64 + qt*32 + l31, unit (kc*2+hi)^(q&7)
    const int q7 = l31 & 7;
    const int prRow0 = (qh2 * 64 + l31) * 128;       // qt=0
    const int prRow1 = prRow0 + 32 * 128;            // qt=1

    f32x16 o00 = (f32x16)0.0f, o01 = (f32x16)0.0f;   // o[ct][qt]
    f32x16 o10 = (f32x16)0.0f, o11 = (f32x16)0.0f;

    barrier_lgkm();                                  // #1

    for (int jt = 0; jt < 64; ++jt) {
      // issue KB frag loads for tile jt (full phase to land across barrier)
      const char* kcb = KBb + (size_t)jt * 32768;
      bf16x8 a00 = *(const bf16x8*)(kcb + 0 * 8192 + cBase);          // ct0
      bf16x8 a01 = *(const bf16x8*)(kcb + 1 * 8192 + cBase);
      bf16x8 a02 = *(const bf16x8*)(kcb + 2 * 8192 + cBase);
      bf16x8 a03 = *(const bf16x8*)(kcb + 3 * 8192 + cBase);
      bf16x8 a10 = *(const bf16x8*)(kcb + 0 * 8192 + cBase + 1024);   // ct1
      bf16x8 a11 = *(const bf16x8*)(kcb + 1 * 8192 + cBase + 1024);
      bf16x8 a12 = *(const bf16x8*)(kcb + 2 * 8192 + cBase + 1024);
      bf16x8 a13 = *(const bf16x8*)(kcb + 3 * 8192 + cBase + 1024);

      barrier_lgkm();                                // #jt+2: P(jt) ready

      const char* pb = PlB + (jt & 1) * 16384;
#pragma unroll
      for (int kc = 0; kc < 4; ++kc) {
        const int uo = (((kc << 1) | hi) ^ q7) << 4;
        bf16x8 p0 = *(const bf16x8*)(pb + prRow0 + uo);
        bf16x8 p1 = *(const bf16x8*)(pb + prRow1 + uo);
        bf16x8 a0 = kc == 0 ? a00 : kc == 1 ? a01 : kc == 2 ? a02 : a03;
        bf16x8 a1 = kc == 0 ? a10 : kc == 1 ? a11 : kc == 2 ? a12 : a13;
        o00 = __builtin_amdgcn_mfma_f32_32x32x16_bf16(a0, p0, o00, 0, 0, 0);
        o01 = __builtin_amdgcn_mfma_f32_32x32x16_bf16(a0, p1, o01, 0, 0, 0);
        o10 = __builtin_amdgcn_mfma_f32_32x32x16_bf16(a1, p0, o10, 0, 0, 0);
        o11 = __builtin_amdgcn_mfma_f32_32x32x16_bf16(a1, p1, o11, 0, 0, 0);
      }
    }

    barrier_lgkm();                                  // #66: lE published

    // epilogue: normalize and store (32x32 C-layout: col=l31,
    // row = (r&3) + 8*(r>>2) + 4*hi)
    const float* lE = (const float*)smem;
    const int qb = qh2 * 64;
    const float rl0 = 1.0f / (lE[qb + l31] + lE[128 + qb + l31]);
    const float rl1 = 1.0f / (lE[qb + 32 + l31] + lE[128 + qb + 32 + l31]);
    float* __restrict__ Ob = Out + (size_t)b * CH * NPIX;
#pragma unroll
    for (int r = 0; r < 16; ++r) {
      const int crow = (r & 3) + 8 * (r >> 2) + 4 * hi;
      float* orow0 = Ob + (size_t)(c0 + crow) * NPIX + q0 + qb;
      float* orow1 = Ob + (size_t)(c0 + 32 + crow) * NPIX + q0 + qb;
      orow0[l31]      = o00[r] * rl0;
      orow0[32 + l31] = o01[r] * rl1;
      orow1[l31]      = o10[r] * rl0;
      orow1[32 + l31] = o11[r] * rl1;
    }
  }
}

// ============================================================================
extern "C" void kernel_launch(void* const* d_in, const int* in_sizes, int n_in,
                              void* d_out, int out_size, void* d_ws, size_t ws_size,
                              hipStream_t stream) {
  const float* F = (const float*)d_in[0];
  float* out = (float*)d_out;
  const size_t imgElems = (size_t)BATCH * NPIX * CH;   // 8.4M bf16 per image

  __bf16* KAi = (__bf16*)d_ws;            // ws >= 33.6 MB (verified rounds 2-9)
  __bf16* KBi = KAi + imgElems;
  ca_prep<<<dim3(BATCH, 128), 256, 0, stream>>>(F, KAi, KBi);
  ca_attn10<<<dim3(BATCH, 32), 1024, 0, stream>>>(F, KAi, KBi, out);
}